// Round 20
// baseline (196.413 us; speedup 1.0000x reference)
//
#include <hip/hip_runtime.h>

#define INFV 1e8f
#define LN2F 0.69314718055994530942f
#define L2EF 1.44269504088896340736f

constexpr int NC = 512;   // DP columns
constexpr int RW = 64;    // rows per wave (1 row per lane)
constexpr int NW = 8;     // waves per block -> 2 waves per SIMD
constexpr int RC = 72;    // ring columns (9 panels of 8)
constexpr int GOFF = 9;   // wave offset in groups (72 steps; R18-proven)
constexpr int NGRP = 72 + 7 * GOFF;  // 135

// R18's proven NW=8 geometry/protocol (2 waves/SIMD, GOFF=9, log-domain
// interface, per-lane scale E) + R19's proven instruction diet:
//  - ring salt REMOVED (R18's 9.5M-conflict poison). Salt-free banks at
//    RW=64: compute b32 -> bank l&31 (2-way, free); panel b32 -> bank y&31
//    (2 lanes/bank, distinct addrs, free); uniform mailbox b128 -> broadcast.
//  - FAST PATH for interior groups (8<=h<=63; u in [1,511] for all lanes):
//    no clamps/validity/cold-start/bp_r; slot = one v%RC + wrap-select;
//    panel helpers hoist (8p)%RC to one mod per call.
//  - mg[] precomputed (INFV for w==0) -> no per-phase selects.
static __device__ __forceinline__ float wave_shr1(float v, float old) {
    // lanes 1..63 <- lane-1's v; lane 0 keeps `old` (bound_ctrl=false)
    return __int_as_float(__builtin_amdgcn_update_dpp(
        __float_as_int(old), __float_as_int(v), 0x138, 0xF, 0xF, false));
}

__global__ __launch_bounds__(512, 1) void sdtw15(const float* __restrict__ D,
                                                 float* __restrict__ O) {
    __shared__ __align__(16) float ring[NW * RC * RW];  // 147456 B
    __shared__ __align__(16) float mbox[7 * NC];        // 14336 B (log R)
    __shared__ int pflag[8];                            // 161824 B total

    const int tid = threadIdx.x;
    const int w = tid >> 6, l = tid & 63;
    const int b = blockIdx.x;

    if (tid < 8) pflag[tid] = 0;
    __syncthreads();  // once; no barriers in the loop

    const float* __restrict__ Dg = D + (size_t)b * NC * 512 + (size_t)w * RW * NC;
    float* __restrict__ Og = O + (size_t)b * NC * 512 + (size_t)w * RW * NC;
    float* __restrict__ rg = ring + w * RC * RW;

    // panel helpers: 64 rows x 8 cols = 128 float4; f = k*64+l, y=f>>1, q=f&1
    float4 st[2];
    auto panel_load = [&](int p) {
#pragma unroll
        for (int k = 0; k < 2; ++k) {
            const int f = k * 64 + l, y = f >> 1, q = f & 1;
            st[k] = *(const float4*)(Dg + (size_t)y * NC + p * 8 + q * 4);
        }
    };
    auto panel_write = [&](int p) {  // stores e^{-D} (true scale)
        const int spb = (p * 8) % RC;  // one mod per call
#pragma unroll
        for (int k = 0; k < 2; ++k) {
            const int f = k * 64 + l, y = f >> 1, q = f & 1;
#pragma unroll
            for (int j = 0; j < 4; ++j)
                rg[(spb + q * 4 + j) * RW + y] = __expf(-((const float*)&st[k])[j]);
        }
    };
    auto panel_flush = [&](int p) {  // ring (R values) -> global
        const int spb = (p * 8) % RC;
#pragma unroll
        for (int k = 0; k < 2; ++k) {
            const int f = k * 64 + l, y = f >> 1, q = f & 1;
            float4 v;
#pragma unroll
            for (int j = 0; j < 4; ++j)
                ((float*)&v)[j] = rg[(spb + q * 4 + j) * RW + y];
            *(float4*)(Og + (size_t)y * NC + p * 8 + q * 4) = v;
        }
    };

    for (int p = 0; p < 9; ++p) { panel_load(p); panel_write(p); }
    panel_load(9);

    float prevP = 0.f;                  // stored P[row l, u-1] = e^{-R} * 2^E
    float E = 0.f;                      // private per-lane scale
    float bp_r = (w == 0 && l == 0) ? 0.f : INFV;  // log R[l-1, u-1] (slow path)
    float r_out = INFV;                 // log R[l, u] for lane l+1
    float vab_prev = 0.f;               // cached P(R[l-1, u-1]) at E
    float carry = INFV;                 // lane63 o carried one group (log)

    for (int g = 0; g < NGRP; ++g) {
        const int h = g - GOFF * w;     // wave-local group index
        if (h < 0 || h > 71) continue;
        const int tb = 8 * h;

        // ---- group start: consumer handshake + mailbox batch read ----
        float mg[8];
        if (w > 0 && h <= 63) {
            const int need = tb + 8;
            int guard = 0;
            while (__hip_atomic_load(&pflag[w - 1], __ATOMIC_ACQUIRE,
                                     __HIP_MEMORY_SCOPE_WORKGROUP) < need &&
                   ++guard < (1 << 24)) {}
            const float4 m0 = *(const float4*)&mbox[(w - 1) * NC + tb];
            const float4 m1 = *(const float4*)&mbox[(w - 1) * NC + tb + 4];
            mg[0] = m0.x; mg[1] = m0.y; mg[2] = m0.z; mg[3] = m0.w;
            mg[4] = m1.x; mg[5] = m1.y; mg[6] = m1.z; mg[7] = m1.w;
        } else {
#pragma unroll
            for (int j = 0; j < 8; ++j) mg[j] = INFV;  // row -1 boundary / w==0
        }

        float mbuf[8];

        if (h >= 8 && h <= 63) {
            // ================= FAST PATH (interior; all lanes valid) =======
            const int v = tb - l;        // in [1, 504]
            const int sb = v % RC;       // one mod
            int ad[8];
            float pdv[8];
#pragma unroll
            for (int ph = 0; ph < 8; ++ph) {
                int a = (sb + ph) * RW + l;
                if (sb + ph >= RC) a -= RC * RW;  // single wrap possible
                ad[ph] = a;
                pdv[ph] = rg[a];
            }
            float obuf[8];
#pragma unroll
            for (int ph = 0; ph < 8; ++ph) {
                const float up_r = wave_shr1(r_out, mg[ph]);     // log R[l-1,u]
                const float vab = __expf(fmaf(E, LN2F, -up_r));  // chain exp
                const float s = (vab_prev + vab) + prevP;        // dab == vab_prev
                const float c = pdv[ph] * s;
                const float o = fmaf(E, LN2F, -__logf(c));
                obuf[ph] = o;
                prevP = c; vab_prev = vab; r_out = o; mbuf[ph] = o;
            }
#pragma unroll
            for (int ph = 0; ph < 8; ++ph) rg[ad[ph]] = obuf[ph];
        } else {
            // ================= SLOW PATH (boundary; R18 verbatim) ==========
            int ad[8];
            float pdv[8];
#pragma unroll
            for (int ph = 0; ph < 8; ++ph) {
                const int c = tb + ph - l;
                const int cs = min(max(c, 0), NC - 1);
                ad[ph] = (cs % RC) * RW + l;
                pdv[ph] = rg[ad[ph]];
            }
            float obuf[8];
#pragma unroll
            for (int ph = 0; ph < 8; ++ph) {
                const int u = tb + ph - l;
                const bool valid = (u >= 0) && (u < NC);
                const float up_r = wave_shr1(r_out, mg[ph]);
                const float dab_log = bp_r;
                bp_r = up_r;
                if (valid) {
                    float dab;
                    if (u == 0) {  // cold start: adopt scale, pin boundary ~2^10
                        E = (w == 0 && l == 0) ? 0.f : floorf(up_r * L2EF) + 10.f;
                        dab = __expf(fmaf(E, LN2F, -dab_log));
                    } else {
                        dab = vab_prev;
                    }
                    const float vab = __expf(fmaf(E, LN2F, -up_r));
                    const float s = (dab + vab) + prevP;
                    const float c = pdv[ph] * s;
                    const float o = fmaf(E, LN2F, -__logf(c));
                    obuf[ph] = o;
                    prevP = c; vab_prev = vab; r_out = o; mbuf[ph] = o;
                } else {
                    mbuf[ph] = INFV;
                }
            }
#pragma unroll
            for (int ph = 0; ph < 8; ++ph) {
                const int u = tb + ph - l;
                if (u >= 0 && u < NC) rg[ad[ph]] = obuf[ph];
            }
        }

        // ---- group end: mailbox write + publish (log domain, R18-proven) ----
        if (w < 7) {
            if (h >= 8 && l == 63) {  // chunk h-8 = cols tb-64..tb-57
                *(float4*)&mbox[w * NC + tb - 64] =
                    make_float4(carry, mbuf[0], mbuf[1], mbuf[2]);
                *(float4*)&mbox[w * NC + tb - 60] =
                    make_float4(mbuf[3], mbuf[4], mbuf[5], mbuf[6]);
            }
            carry = mbuf[7];
            if (h >= 8 && l == 0) {
                __hip_atomic_store(&pflag[w], tb - 56, __ATOMIC_RELEASE,
                                   __HIP_MEMORY_SCOPE_WORKGROUP);
            }
        }

        // ---- group end: renorm (pin stored prevP ~2^10; log r_out immune) ----
        {
            const int ex = (int)((__float_as_uint(prevP) >> 23) & 0xffu);
            if (ex != 0) {  // skip not-yet-started lanes
                const int sh = 137 - ex;
                const float f = __uint_as_float((unsigned)(sh + 127) << 23);
                E += (float)sh;
                prevP *= f; vab_prev *= f;
            }
        }

        // ---- group end: panel event (private ring; proven ordering) ----
        if (h >= 8) {
            panel_flush(h - 8);
            if (h + 1 < 64) {
                panel_write(h + 1);
                if (h + 2 < 64) panel_load(h + 2);
            }
        }
    }
}

extern "C" void kernel_launch(void* const* d_in, const int* in_sizes, int n_in,
                              void* d_out, int out_size, void* d_ws, size_t ws_size,
                              hipStream_t stream) {
    const float* D = (const float*)d_in[0];
    float* out = (float*)d_out;
    const int B = in_sizes[0] / (512 * 512);
    sdtw15<<<B, 512, 0, stream>>>(D, out);
}

// Round 21
// 189.739 us; speedup vs baseline: 1.0352x; 1.0352x over previous
//
#include <hip/hip_runtime.h>

#define INFV 1e8f
#define LN2F 0.69314718055994530942f
#define L2EF 1.44269504088896340736f

constexpr int NC = 512;   // DP columns
constexpr int RW = 128;   // rows per wave
constexpr int NW = 4;     // waves per block
constexpr int RC = 72;    // ring columns (9 panels of 8)
constexpr int GOFF = 10;  // wave offset in groups (80 steps; 1-group slack)
constexpr int NGRP = 72 + 3 * GOFF;  // 102

// R19 host (NW=4, 2 rows/lane, salt-free private ring, fast/slow path,
// log-domain interface, per-lane E) + GROUP-BOUNDARY SOFTWARE PIPELINE:
// group h+1's handshake/mailbox-read and pd pre-reads are issued at the END
// of group h (after panel_write(h+1)), so their LDS latency overlaps the
// group tail (renorm/flags/branch) instead of stalling the next group's
// entry. Safety: with GOFF=10 the producer has published cnt = 8h+24 >=
// need 8h+16 by consumer group-h end (one-group slack); prefetched cols
// (tb+8..tb+15 per lane-row) are disjoint from every write between issue
// and consumption (per-lane row ownership; panel_write(h+1) precedes).
static __device__ __forceinline__ float wave_shr1(float v, float old) {
    // lanes 1..63 <- lane-1's v; lane 0 keeps `old` (bound_ctrl=false)
    return __int_as_float(__builtin_amdgcn_update_dpp(
        __float_as_int(old), __float_as_int(v), 0x138, 0xF, 0xF, false));
}

__global__ __launch_bounds__(256, 1) void sdtw16(const float* __restrict__ D,
                                                 float* __restrict__ O) {
    __shared__ __align__(16) float ring[NW * RC * RW];  // 147456 B
    __shared__ __align__(16) float mbox[3 * NC];        // 6144 B (log R)
    __shared__ int pflag[4];

    const int tid = threadIdx.x;
    const int w = tid >> 6, l = tid & 63;
    const int b = blockIdx.x;

    if (tid < 4) pflag[tid] = 0;
    __syncthreads();  // once; no barriers in the loop

    const float* __restrict__ Dg = D + (size_t)b * NC * 512 + (size_t)w * RW * NC;
    float* __restrict__ Og = O + (size_t)b * NC * 512 + (size_t)w * RW * NC;
    float* __restrict__ rg = ring + w * RC * RW;

    // panel helpers: 128 rows x 8 cols; f = k*64+l, y = f>>1, q = f&1.
    float4 st[4];
    auto panel_load = [&](int p) {
#pragma unroll
        for (int k = 0; k < 4; ++k) {
            const int f = k * 64 + l, y = f >> 1, q = f & 1;
            st[k] = *(const float4*)(Dg + (size_t)y * NC + p * 8 + q * 4);
        }
    };
    auto panel_write = [&](int p) {  // stores e^{-D} (true scale)
        const int spb = (p * 8) % RC;  // one mod per call
#pragma unroll
        for (int k = 0; k < 4; ++k) {
            const int f = k * 64 + l, y = f >> 1, q = f & 1;
#pragma unroll
            for (int j = 0; j < 4; ++j)
                rg[(spb + q * 4 + j) * RW + y] = __expf(-((const float*)&st[k])[j]);
        }
    };
    auto panel_flush = [&](int p) {  // ring (R values) -> global
        const int spb = (p * 8) % RC;
#pragma unroll
        for (int k = 0; k < 4; ++k) {
            const int f = k * 64 + l, y = f >> 1, q = f & 1;
            float4 v;
#pragma unroll
            for (int j = 0; j < 4; ++j)
                ((float*)&v)[j] = rg[(spb + q * 4 + j) * RW + y];
            *(float4*)(Og + (size_t)y * NC + p * 8 + q * 4) = v;
        }
    };

    for (int p = 0; p < 9; ++p) { panel_load(p); panel_write(p); }
    panel_load(9);

    const int y0 = 2 * l;
    float prevP0 = 0.f, prevP1 = 0.f;  // stored P[row, u-1] = e^{-R} * 2^E
    float h01 = 0.f;                   // prevP0 + prevP1
    float E = 0.f;                     // private per-lane scale
    float bp_r = (w == 0 && l == 0) ? 0.f : INFV;  // log R[above, u-1] (slow path)
    float r_out = INFV;                // log R[y0+1, u] for next lane
    float vab_prev = 0.f;              // cached P(R[above, u-1]) at E
    float carry = INFV;                // lane63 o1 carried one group

    // pipelined group-state (filled at end of previous group, or at h==0)
    float mgN[8];
    float2 pdvN[8];
    int adN[8];

    // prefetch group x's mailbox chunk + pd operands into mgN/pdvN/adN
    auto prefetch_state = [&](int x) {
        const int tbx = 8 * x;
        if (w > 0 && x <= 63) {
            const int need = tbx + 8;
            int guard = 0;
            while (__hip_atomic_load(&pflag[w - 1], __ATOMIC_ACQUIRE,
                                     __HIP_MEMORY_SCOPE_WORKGROUP) < need &&
                   ++guard < (1 << 24)) {}
            const float4 m0 = *(const float4*)&mbox[(w - 1) * NC + tbx];
            const float4 m1 = *(const float4*)&mbox[(w - 1) * NC + tbx + 4];
            mgN[0] = m0.x; mgN[1] = m0.y; mgN[2] = m0.z; mgN[3] = m0.w;
            mgN[4] = m1.x; mgN[5] = m1.y; mgN[6] = m1.z; mgN[7] = m1.w;
        } else {
#pragma unroll
            for (int j = 0; j < 8; ++j) mgN[j] = INFV;
        }
        if (x >= 8 && x <= 63) {  // fast-range addressing
            const int v = tbx - l;   // in [1, 504]
            const int sb = v % RC;   // one mod
#pragma unroll
            for (int ph = 0; ph < 8; ++ph) {
                int a = (sb + ph) * RW + y0;
                if (sb + ph >= RC) a -= RC * RW;  // single wrap
                adN[ph] = a;
                pdvN[ph] = *(const float2*)&rg[a];
            }
        } else {  // boundary: clamped
#pragma unroll
            for (int ph = 0; ph < 8; ++ph) {
                const int c = tbx + ph - l;
                const int cs = min(max(c, 0), NC - 1);
                adN[ph] = (cs % RC) * RW + y0;
                pdvN[ph] = *(const float2*)&rg[adN[ph]];
            }
        }
    };

    for (int g = 0; g < NGRP; ++g) {
        const int h = g - GOFF * w;
        if (h < 0 || h > 71) continue;
        const int tb = 8 * h;

        if (h == 0) prefetch_state(0);  // first active group: inline fill

        float mbuf[8];

        if (h >= 8 && h <= 63) {
            // ================= FAST PATH (interior; all lanes valid) =======
            float2 obuf[8];
#pragma unroll
            for (int ph = 0; ph < 8; ++ph) {
                const float up_r = wave_shr1(r_out, mgN[ph]);    // log R[y0-1,u]
                const float vab = __expf(fmaf(E, LN2F, -up_r));  // chain exp
                const float s0 = (vab_prev + vab) + prevP0;      // dab == vab_prev
                const float c0 = pdvN[ph].x * s0;
                const float s1 = h01 + c0;
                const float c1 = pdvN[ph].y * s1;
                const float o0 = fmaf(E, LN2F, -__logf(c0));
                const float o1 = fmaf(E, LN2F, -__logf(c1));
                obuf[ph] = make_float2(o0, o1);
                prevP0 = c0; prevP1 = c1; h01 = c0 + c1;
                vab_prev = vab; r_out = o1; mbuf[ph] = o1;
            }
#pragma unroll
            for (int ph = 0; ph < 8; ++ph) *(float2*)&rg[adN[ph]] = obuf[ph];
        } else {
            // ================= SLOW PATH (boundary; R19 verbatim) ==========
            float2 obuf[8];
#pragma unroll
            for (int ph = 0; ph < 8; ++ph) {
                const int u = tb + ph - l;
                const bool valid = (u >= 0) && (u < NC);
                const float up_r = wave_shr1(r_out, mgN[ph]);
                const float dab_log = bp_r;
                bp_r = up_r;
                if (valid) {
                    float dab;
                    if (u == 0) {  // cold start: adopt scale, pin boundary ~2^10
                        E = (w == 0 && l == 0) ? 0.f : floorf(up_r * L2EF) + 10.f;
                        dab = __expf(fmaf(E, LN2F, -dab_log));
                    } else {
                        dab = vab_prev;
                    }
                    const float vab = __expf(fmaf(E, LN2F, -up_r));
                    const float s0 = (dab + vab) + prevP0;
                    const float c0 = pdvN[ph].x * s0;
                    const float s1 = h01 + c0;
                    const float c1 = pdvN[ph].y * s1;
                    const float o0 = fmaf(E, LN2F, -__logf(c0));
                    const float o1 = fmaf(E, LN2F, -__logf(c1));
                    obuf[ph] = make_float2(o0, o1);
                    prevP0 = c0; prevP1 = c1; h01 = c0 + c1;
                    vab_prev = vab; r_out = o1; mbuf[ph] = o1;
                } else {
                    mbuf[ph] = INFV;
                }
            }
#pragma unroll
            for (int ph = 0; ph < 8; ++ph) {
                const int u = tb + ph - l;
                if (u >= 0 && u < NC) *(float2*)&rg[adN[ph]] = obuf[ph];
            }
        }

        // ---- group end: mailbox write + publish (log domain) ----
        if (w < 3) {
            if (h >= 8 && l == 63) {  // chunk h-8 = cols tb-64..tb-57
                *(float4*)&mbox[w * NC + tb - 64] =
                    make_float4(carry, mbuf[0], mbuf[1], mbuf[2]);
                *(float4*)&mbox[w * NC + tb - 60] =
                    make_float4(mbuf[3], mbuf[4], mbuf[5], mbuf[6]);
            }
            carry = mbuf[7];
            if (h >= 8 && l == 0) {
                __hip_atomic_store(&pflag[w], tb - 56, __ATOMIC_RELEASE,
                                   __HIP_MEMORY_SCOPE_WORKGROUP);
            }
        }

        // ---- group end: renorm (pin stored prevP0 ~2^10; log r_out immune) --
        {
            const int ex = (int)((__float_as_uint(prevP0) >> 23) & 0xffu);
            if (ex != 0) {
                const int sh = 137 - ex;
                const float f = __uint_as_float((unsigned)(sh + 127) << 23);
                E += (float)sh;
                prevP0 *= f; prevP1 *= f; h01 *= f; vab_prev *= f;
            }
        }

        // ---- group end: panel event (private ring; proven ordering) ----
        if (h >= 8) {
            panel_flush(h - 8);
            if (h + 1 < 64) {
                panel_write(h + 1);
                if (h + 2 < 64) panel_load(h + 2);
            }
        }

        // ---- group end: prefetch next group's inputs (overlaps tail) ----
        if (h < 71) prefetch_state(h + 1);
    }
}

extern "C" void kernel_launch(void* const* d_in, const int* in_sizes, int n_in,
                              void* d_out, int out_size, void* d_ws, size_t ws_size,
                              hipStream_t stream) {
    const float* D = (const float*)d_in[0];
    float* out = (float*)d_out;
    const int B = in_sizes[0] / (512 * 512);
    sdtw16<<<B, 256, 0, stream>>>(D, out);
}